// Round 5
// baseline (260.330 us; speedup 1.0000x reference)
//
#include <hip/hip_runtime.h>
#include <math.h>

#define N_NODES 50000
#define N_EDGES 800000
#define FD 128

#define NBUCK 256         // buckets: dst>>8 -> 0..195 used
#define NBUSED 196        // ceil(50000/256)
#define BCAP  6144        // entries per bucket (mean 4096, sigma~64 -> +32 sigma)
#define MAXIT 24          // BCAP/256

// ---- workspace layout (bytes) ----
#define WS_BCUR   0u          // int[256] (memset 1024 B)
#define WS_OFF    400256u     // int[N+1] -> 600260 (written fully by uber_k)
#define WS_ESRC   601728u     // ushort[E] -> 2201728
#define WS_WT     3801600u    // bf16[8*128*128] -> 4063744
#define WS_HB     16863744u   // bf16[N*128]; ALSO aliased as bin staging (disjoint lifetime)
#define WS_STAGE  16863744u   // uint32[196*6144] = 4.82 MB -> 21680640
#define WS_Q      29663744u   // bf16[N*128]
#define WS_KV     42463744u   // fp8[N*256] interleaved k|v -> 55263744
#define WS_S      68063744u   // bf16[N*128], ends 80863744

typedef unsigned short ushort_t;
typedef unsigned int uint_t;
typedef unsigned char uchar_t;
typedef __attribute__((ext_vector_type(8))) short short8;
typedef __attribute__((ext_vector_type(4))) float floatx4;
typedef __attribute__((ext_vector_type(2))) float floatx2;

__device__ __forceinline__ ushort_t f2bf(float f) {
    uint_t u = __float_as_uint(f);
    return (ushort_t)((u + 0x7FFFu + ((u >> 16) & 1u)) >> 16);   // RNE
}
__device__ __forceinline__ float bf2f_lo(uint_t u) { return __uint_as_float(u << 16); }
__device__ __forceinline__ float bf2f_hi(uint_t u) { return __uint_as_float(u & 0xFFFF0000u); }

// ---------------- prep: W->W^T bf16 (blocks 0..63) + edge binning (64..) ----------------
__global__ __launch_bounds__(256) void prep_k(
    const float* __restrict__ W0, const float* __restrict__ W1,
    const float* __restrict__ W2, const float* __restrict__ W3,
    const float* __restrict__ W4, const float* __restrict__ W5,
    const float* __restrict__ W6, const float* __restrict__ W7,
    ushort_t* __restrict__ Wt,
    const int* __restrict__ ei,
    int* __restrict__ bcur, uint_t* __restrict__ staging)
{
    if (blockIdx.x < 64) {
        const int m = blockIdx.x >> 3;
        const int sl = blockIdx.x & 7;
        const float* W = (m==0)?W0:(m==1)?W1:(m==2)?W2:(m==3)?W3:(m==4)?W4:(m==5)?W5:(m==6)?W6:W7;
        ushort_t* O = Wt + m * (FD * FD);
        #pragma unroll
        for (int it = 0; it < 2; ++it) {
            int i = threadIdx.x + it * 256 + sl * 512;   // 0..4095
            int n = i & 127, k4 = (i >> 7) << 2;
            ushort_t p[4];
            p[0] = f2bf(W[(k4 + 0) * FD + n]);
            p[1] = f2bf(W[(k4 + 1) * FD + n]);
            p[2] = f2bf(W[(k4 + 2) * FD + n]);
            p[3] = f2bf(W[(k4 + 3) * FD + n]);
            *(ushort4*)(O + n * FD + k4) = *(ushort4*)p;   // Wt[n][k]
        }
    } else {
        __shared__ int lhist[NBUCK];
        __shared__ int lbase[NBUCK];
        const int tid = threadIdx.x;
        const int base = (blockIdx.x - 64) * 2048 + tid * 8;   // E % 8 == 0
        lhist[tid] = 0;
        __syncthreads();

        uint_t pk[8];
        int li[8];
        const bool act = (base < N_EDGES);
        if (act) {
            int4 s0 = *(const int4*)(ei + base);
            int4 s1 = *(const int4*)(ei + base + 4);
            int4 d0 = *(const int4*)(ei + N_EDGES + base);
            int4 d1 = *(const int4*)(ei + N_EDGES + base + 4);
            int srcs[8] = {s0.x, s0.y, s0.z, s0.w, s1.x, s1.y, s1.z, s1.w};
            int dsts[8] = {d0.x, d0.y, d0.z, d0.w, d1.x, d1.y, d1.z, d1.w};
            #pragma unroll
            for (int j = 0; j < 8; ++j) {
                li[j] = atomicAdd(&lhist[dsts[j] >> 8], 1);
                pk[j] = (uint_t)srcs[j] | ((uint_t)dsts[j] << 16);
            }
        }
        __syncthreads();
        lbase[tid] = atomicAdd(&bcur[tid], lhist[tid]);
        __syncthreads();
        if (act) {
            #pragma unroll
            for (int j = 0; j < 8; ++j) {
                int bk = pk[j] >> 24;       // dst>>8
                staging[bk * BCAP + lbase[bk] + li[j]] = pk[j];
            }
        }
    }
}

// ---------------- shared GEMM body: 128-row tile, O_m = X @ W_m + b_m, m=0..3 ----------------
// Each wave owns 32 rows (two 16-row halves sharing every B fragment).
// 70 KB LDS -> 2 blocks/CU; half the blocks/B-staging/barriers of the 64-row tile.
__device__ __forceinline__ void gemm_body(
    int bid, ushort_t (*As)[136], ushort_t (*Bs)[136],
    const void* __restrict__ Xin, int x_is_fp32,
    const ushort_t* __restrict__ Wt,
    const float* __restrict__ b0, const float* __restrict__ b1,
    const float* __restrict__ b2, const float* __restrict__ b3,
    ushort_t* __restrict__ Oq, uchar_t* __restrict__ Okv,
    ushort_t* __restrict__ Os, int N)
{
    const int tid = threadIdx.x;
    const int row0 = bid * 128;

    // ---- stage X tile (128 rows) ----
    if (x_is_fp32) {
        const float* Xf = (const float*)Xin;
        #pragma unroll
        for (int it = 0; it < 16; ++it) {
            int i = tid + it * 256;          // 4096 float4 chunks
            int r = i >> 5, c4 = (i & 31) * 4;
            int gr = row0 + r;
            float4 xv = make_float4(0.f, 0.f, 0.f, 0.f);
            if (gr < N) xv = *(const float4*)(Xf + (size_t)gr * FD + c4);
            ushort_t p[4] = {f2bf(xv.x), f2bf(xv.y), f2bf(xv.z), f2bf(xv.w)};
            *(ushort4*)(&As[r][c4]) = *(ushort4*)p;
        }
    } else {
        const ushort_t* Xb = (const ushort_t*)Xin;
        #pragma unroll
        for (int it = 0; it < 8; ++it) {
            int i = tid + it * 256;          // 2048 x 16B chunks
            int r = i >> 4, c8 = (i & 15) * 8;
            int gr = row0 + r;
            uint4 val = make_uint4(0, 0, 0, 0);
            if (gr < N) val = *(const uint4*)(Xb + (size_t)gr * FD + c8);
            *(uint4*)(&As[r][c8]) = val;
        }
    }
    __syncthreads();

    const int wid = tid >> 6, lane = tid & 63;
    const int quad = lane >> 4, col_l = lane & 15;

    // ---- hoist A fragments: wave covers rows wid*32 .. wid*32+31 ----
    short8 afr0[4], afr1[4];
    #pragma unroll
    for (int ks = 0; ks < 4; ++ks) {
        afr0[ks] = *(const short8*)(&As[wid * 32 + col_l][ks * 32 + quad * 8]);
        afr1[ks] = *(const short8*)(&As[wid * 32 + 16 + col_l][ks * 32 + quad * 8]);
    }

    #pragma unroll 1
    for (int m = 0; m < 4; ++m) {
        const ushort_t* Wm = Wt + m * (FD * FD);
        const float* B = (m == 0) ? b0 : (m == 1) ? b1 : (m == 2) ? b2 : b3;

        // stage Bs = W^T[m] (straight copy, coalesced, padded rows)
        #pragma unroll
        for (int it = 0; it < 8; ++it) {
            int i = tid + it * 256;          // 2048 x 16B chunks
            int r = i >> 4, c8 = (i & 15) * 8;
            *(uint4*)(&Bs[r][c8]) = *(const uint4*)(Wm + (size_t)r * FD + c8);
        }
        __syncthreads();   // Bs ready; also orders prev C-tile reads vs new C-writes

        floatx4 acc0[8], acc1[8];
        #pragma unroll
        for (int nt = 0; nt < 8; ++nt) {
            acc0[nt] = (floatx4){0.f, 0.f, 0.f, 0.f};
            acc1[nt] = (floatx4){0.f, 0.f, 0.f, 0.f};
        }

        #pragma unroll
        for (int ks = 0; ks < 4; ++ks) {
            const int kb = ks * 32 + quad * 8;
            #pragma unroll
            for (int nt = 0; nt < 8; ++nt) {
                short8 b = *(const short8*)(&Bs[nt * 16 + col_l][kb]);   // shared by both halves
                acc0[nt] = __builtin_amdgcn_mfma_f32_16x16x32_bf16(afr0[ks], b, acc0[nt], 0, 0, 0);
                acc1[nt] = __builtin_amdgcn_mfma_f32_16x16x32_bf16(afr1[ks], b, acc1[nt], 0, 0, 0);
            }
        }

        // C -> LDS (reuse As), add bias
        #pragma unroll
        for (int nt = 0; nt < 8; ++nt) {
            const int col = nt * 16 + col_l;
            const float bv = B[col];
            #pragma unroll
            for (int r = 0; r < 4; ++r) {
                As[wid * 32 + quad * 4 + r][col]      = f2bf(acc0[nt][r] + bv);
                As[wid * 32 + 16 + quad * 4 + r][col] = f2bf(acc1[nt][r] + bv);
            }
        }
        __syncthreads();   // C tile ready

        if (m == 1 || m == 2) {
            // k/v output: bf16 C tile -> fp8 e4m3, interleaved kv row (k at +0, v at +128)
            uchar_t* O8 = Okv + ((m == 1) ? 0 : 128);
            #pragma unroll
            for (int it = 0; it < 8; ++it) {
                int i = tid + it * 256;      // 2048 chunks of 8 cols
                int r = i >> 4, c8 = (i & 15) * 8;
                int gr = row0 + r;
                if (gr < N) {
                    uint4 cb = *(const uint4*)(&As[r][c8]);
                    int lo = __builtin_amdgcn_cvt_pk_fp8_f32(bf2f_lo(cb.x), bf2f_hi(cb.x), 0, false);
                    lo = __builtin_amdgcn_cvt_pk_fp8_f32(bf2f_lo(cb.y), bf2f_hi(cb.y), lo, true);
                    int hi = __builtin_amdgcn_cvt_pk_fp8_f32(bf2f_lo(cb.z), bf2f_hi(cb.z), 0, false);
                    hi = __builtin_amdgcn_cvt_pk_fp8_f32(bf2f_lo(cb.w), bf2f_hi(cb.w), hi, true);
                    *(uint2*)(O8 + ((size_t)gr << 8) + c8) = make_uint2((uint_t)lo, (uint_t)hi);
                }
            }
        } else {
            ushort_t* O = (m == 0) ? Oq : Os;
            #pragma unroll
            for (int it = 0; it < 8; ++it) {
                int i = tid + it * 256;      // 2048 x 16B chunks
                int r = i >> 4, c8 = (i & 15) * 8;
                int gr = row0 + r;
                if (gr < N) *(uint4*)(O + (size_t)gr * FD + c8) = *(const uint4*)(&As[r][c8]);
            }
        }
    }
}

// standalone GEMM (layer 2)
__global__ __launch_bounds__(256) void gemm_mfma_k(
    const void* __restrict__ Xin, int x_is_fp32,
    const ushort_t* __restrict__ Wt,
    const float* __restrict__ b0, const float* __restrict__ b1,
    const float* __restrict__ b2, const float* __restrict__ b3,
    ushort_t* __restrict__ Oq, uchar_t* __restrict__ Okv,
    ushort_t* __restrict__ Os, int N)
{
    __shared__ ushort_t As[128][136];
    __shared__ ushort_t Bs[128][136];
    gemm_body(blockIdx.x, As, Bs, Xin, x_is_fp32, Wt, b0, b1, b2, b3, Oq, Okv, Os, N);
}

// ---------------- uber: per-bucket CSR build (blocks 0..195) + layer-1 GEMM (196..) ----------------
__global__ __launch_bounds__(256) void uber_k(
    const uint_t* __restrict__ staging, const int* __restrict__ bcur,
    int* __restrict__ off, ushort_t* __restrict__ esrc,
    const void* __restrict__ Xin, const ushort_t* __restrict__ Wt,
    const float* __restrict__ b0, const float* __restrict__ b1,
    const float* __restrict__ b2, const float* __restrict__ b3,
    ushort_t* __restrict__ Oq, uchar_t* __restrict__ Okv,
    ushort_t* __restrict__ Os, int N)
{
    __shared__ ushort_t As[128][136];
    __shared__ ushort_t Bs[128][136];
    __shared__ int s_base, s_cnt;

    if (blockIdx.x >= NBUSED) {
        gemm_body(blockIdx.x - NBUSED, As, Bs, Xin, 1, Wt, b0, b1, b2, b3, Oq, Okv, Os, N);
        return;
    }

    const int b = blockIdx.x;
    const int tid = threadIdx.x;
    int* lds  = (int*)&As[0][0];
    int* hist = lds;                      // [256] counts -> exclusive bases
    int* sbuf = lds + 256;                // [256] scan buffer

    // bucket-count prefix (parallel scan over bcur)
    int bc = (tid < NBUSED) ? bcur[tid] : 0;
    sbuf[tid] = bc;
    __syncthreads();
    #pragma unroll
    for (int d = 1; d < 256; d <<= 1) {
        int t = (tid >= d) ? sbuf[tid - d] : 0;
        __syncthreads();
        sbuf[tid] += t;
        __syncthreads();
    }
    if (tid == b) { s_base = sbuf[tid] - bc; s_cnt = bc; }
    hist[tid] = 0;
    __syncthreads();
    const int count = s_cnt;
    const int base  = s_base;
    const uint_t* st = staging + b * BCAP;

    // phase 1: histogram + per-edge rank (single LDS-atomic pass)
    int li[MAXIT];
    #pragma unroll
    for (int it = 0; it < MAXIT; ++it) {
        int i = tid + it * 256;
        if (i < count) {
            int d = (st[i] >> 16) & 255;
            li[it] = atomicAdd(&hist[d], 1);
        }
    }
    __syncthreads();

    // phase 2: exclusive scan of hist[256] (1 per thread)
    int h = hist[tid];
    sbuf[tid] = h;
    __syncthreads();
    #pragma unroll
    for (int d = 1; d < 256; d <<= 1) {
        int t = (tid >= d) ? sbuf[tid - d] : 0;
        __syncthreads();
        sbuf[tid] += t;
        __syncthreads();
    }
    const int excl = sbuf[tid] - h;
    hist[tid] = excl;
    const int dst = (b << 8) + tid;
    if (dst < N) off[dst] = base + excl;
    if (b == 0 && tid == 0) off[N] = N_EDGES;
    __syncthreads();

    // phase 3: atomic-free scatter
    #pragma unroll
    for (int it = 0; it < MAXIT; ++it) {
        int i = tid + it * 256;
        if (i < count) {
            uint_t pkv = st[i];
            int d = (pkv >> 16) & 255;
            esrc[base + hist[d] + li[it]] = (ushort_t)(pkv & 0xFFFFu);
        }
    }
}

// ---------------- per-dst attention ----------------
// 4 lane-groups of 16; 4 edge slots per group -> 16 edges per iteration.
// Interleaved fp8 kv rows (256 B: k|v adjacent), packed f32 math, packed reductions.
__global__ __launch_bounds__(256) void attn_k(
    const ushort_t* __restrict__ q, const uchar_t* __restrict__ kv8,
    const ushort_t* __restrict__ sp,
    const int* __restrict__ off, const ushort_t* __restrict__ esrc,
    ushort_t* __restrict__ out_bf, float* __restrict__ out_f,
    int relu, int bf16out, int N)
{
    const int wid = threadIdx.x >> 6;
    const int lane = threadIdx.x & 63;
    const int g = lane >> 4;         // edge-slot lane-group 0..3
    const int j = lane & 15;         // feature slice within group (8 feats)
    const int dst = blockIdx.x * 4 + wid;
    if (dst >= N) return;

    const int beg = off[dst];
    const int end = off[dst + 1];
    const int f0 = j * 8;

    const uint4 qu = *(const uint4*)(q + ((size_t)dst << 7) + f0);   // 8 bf16
    floatx2 qf2[4];
    qf2[0] = (floatx2){bf2f_lo(qu.x), bf2f_hi(qu.x)};
    qf2[1] = (floatx2){bf2f_lo(qu.y), bf2f_hi(qu.y)};
    qf2[2] = (floatx2){bf2f_lo(qu.z), bf2f_hi(qu.z)};
    qf2[3] = (floatx2){bf2f_lo(qu.w), bf2f_hi(qu.w)};

    const float scale2 = 0.1275174477f;   // (1/sqrt(128)) * log2(e)
    float l = 0.f;
    floatx2 acc2[4];
    #pragma unroll
    for (int i = 0; i < 4; ++i) acc2[i] = (floatx2){0.f, 0.f};

    const int last = end - 1;
    for (int base = beg; base < end; base += 16) {
        // ---- 16 edges: slot c covers edges base+c*4+g across the 4 groups ----
        int e[4], s[4];
        #pragma unroll
        for (int c = 0; c < 4; ++c) {
            e[c] = base + c * 4 + g;
            int idx = (e[c] <= last) ? e[c] : last;
            s[c] = esrc[idx];
        }
        uint2 kk[4], vv[4];
        #pragma unroll
        for (int c = 0; c < 4; ++c) {
            const uchar_t* row = kv8 + ((uint_t)s[c] << 8) + f0;
            kk[c] = *(const uint2*)(row);         // 8 fp8 of k
            vv[c] = *(const uint2*)(row + 128);   // 8 fp8 of v (same 256B row)
        }

        // ---- QK partial dots (packed f32) ----
        float p[4];
        #pragma unroll
        for (int c = 0; c < 4; ++c) {
            floatx2 ka = __builtin_amdgcn_cvt_pk_f32_fp8(kk[c].x, false);
            floatx2 kb = __builtin_amdgcn_cvt_pk_f32_fp8(kk[c].x, true);
            floatx2 kc = __builtin_amdgcn_cvt_pk_f32_fp8(kk[c].y, false);
            floatx2 kd = __builtin_amdgcn_cvt_pk_f32_fp8(kk[c].y, true);
            floatx2 pa = qf2[0] * ka;
            pa = qf2[1] * kb + pa;
            pa = qf2[2] * kc + pa;
            pa = qf2[3] * kd + pa;
            p[c] = pa.x + pa.y;
        }

        // ---- 16-lane reduction of 4 logits (two packed pairs) ----
        floatx2 p01 = {p[0], p[1]};
        floatx2 p23 = {p[2], p[3]};
        #pragma unroll
        for (int i = 1; i <= 8; i <<= 1) {
            long long t0 = __shfl_xor(*(long long*)&p01, i, 64);
            long long t1 = __shfl_xor(*(long long*)&p23, i, 64);
            p01 += *(const floatx2*)&t0;
            p23 += *(const floatx2*)&t1;
        }
        p01 *= scale2;
        p23 *= scale2;

        float w[4];
        w[0] = __builtin_amdgcn_exp2f(p01.x);
        w[1] = __builtin_amdgcn_exp2f(p01.y);
        w[2] = __builtin_amdgcn_exp2f(p23.x);
        w[3] = __builtin_amdgcn_exp2f(p23.y);
        #pragma unroll
        for (int c = 0; c < 4; ++c)
            if (e[c] > last) w[c] = 0.f;

        l += (w[0] + w[1]) + (w[2] + w[3]);

        // ---- PV accumulate (packed f32) ----
        #pragma unroll
        for (int c = 0; c < 4; ++c) {
            floatx2 va = __builtin_amdgcn_cvt_pk_f32_fp8(vv[c].x, false);
            floatx2 vb = __builtin_amdgcn_cvt_pk_f32_fp8(vv[c].x, true);
            floatx2 vc = __builtin_amdgcn_cvt_pk_f32_fp8(vv[c].y, false);
            floatx2 vd = __builtin_amdgcn_cvt_pk_f32_fp8(vv[c].y, true);
            const floatx2 wv = {w[c], w[c]};
            acc2[0] = wv * va + acc2[0];
            acc2[1] = wv * vb + acc2[1];
            acc2[2] = wv * vc + acc2[2];
            acc2[3] = wv * vd + acc2[3];
        }
    }

    // ---- cross-group reduction (xor 16, 32) ----
    #pragma unroll
    for (int i = 0; i < 4; ++i) {
        long long t = __shfl_xor(*(long long*)&acc2[i], 16, 64);
        acc2[i] += *(const floatx2*)&t;
        t = __shfl_xor(*(long long*)&acc2[i], 32, 64);
        acc2[i] += *(const floatx2*)&t;
    }
    l += __shfl_xor(l, 16, 64);
    l += __shfl_xor(l, 32, 64);

    const float inv = 1.0f / ((l == 0.f) ? 1.f : l);
    const int fo = f0 + g * 2;                          // lane stores 2 feats
    const uint_t su = *(const uint_t*)(sp + ((size_t)dst << 7) + fo);
    float ox = acc2[g].x * inv + bf2f_lo(su);
    float oy = acc2[g].y * inv + bf2f_hi(su);
    if (relu) { ox = fmaxf(ox, 0.f); oy = fmaxf(oy, 0.f); }
    if (bf16out) {
        ushort_t p2[2] = {f2bf(ox), f2bf(oy)};
        *(uint_t*)(out_bf + ((size_t)dst << 7) + fo) = *(uint_t*)p2;
    } else {
        *(float2*)(out_f + ((size_t)dst << 7) + fo) = make_float2(ox, oy);
    }
}

// ---------------- launch ----------------
extern "C" void kernel_launch(void* const* d_in, const int* in_sizes, int n_in,
                              void* d_out, int out_size, void* d_ws, size_t ws_size,
                              hipStream_t stream) {
    const float* x  = (const float*)d_in[0];
    const int*   ei = (const int*)d_in[1];   // [2,E]: row0=src, row1=dst
    const float* Wq1 = (const float*)d_in[2],  *bq1 = (const float*)d_in[3];
    const float* Wk1 = (const float*)d_in[4],  *bk1 = (const float*)d_in[5];
    const float* Wv1 = (const float*)d_in[6],  *bv1 = (const float*)d_in[7];
    const float* Ws1 = (const float*)d_in[8],  *bs1 = (const float*)d_in[9];
    const float* Wq2 = (const float*)d_in[10], *bq2 = (const float*)d_in[11];
    const float* Wk2 = (const float*)d_in[12], *bk2 = (const float*)d_in[13];
    const float* Wv2 = (const float*)d_in[14], *bv2 = (const float*)d_in[15];
    const float* Ws2 = (const float*)d_in[16], *bs2 = (const float*)d_in[17];

    char* ws = (char*)d_ws;
    int* bcur    = (int*)(ws + WS_BCUR);
    int* off     = (int*)(ws + WS_OFF);
    ushort_t* esrc = (ushort_t*)(ws + WS_ESRC);
    ushort_t* wt = (ushort_t*)(ws + WS_WT);
    uint_t* staging = (uint_t*)(ws + WS_STAGE);
    ushort_t* hb = (ushort_t*)(ws + WS_HB);
    ushort_t* q  = (ushort_t*)(ws + WS_Q);
    uchar_t*  kv8 = (uchar_t*)(ws + WS_KV);
    ushort_t* s  = (ushort_t*)(ws + WS_S);
    float* out = (float*)d_out;

    const int gblocks = (N_NODES + 127) / 128;        // 391
    const int attn_blocks = (N_NODES + 3) / 4;        // 12500
    const int binblocks = (N_EDGES + 2047) / 2048;    // 391

    // zero bucket cursors only
    hipMemsetAsync(ws + WS_BCUR, 0, 1024, stream);

    // fused: weight transpose (blocks 0..63) + edge binning (64..)
    prep_k<<<64 + binblocks, 256, 0, stream>>>(Wq1, Wk1, Wv1, Ws1, Wq2, Wk2, Wv2, Ws2,
                                               wt, ei, bcur, staging);

    // fused: per-bucket CSR build (196 blocks) + layer-1 GEMM (391 blocks)
    uber_k<<<NBUSED + gblocks, 256, 0, stream>>>(staging, bcur, off, esrc,
                                                 x, wt, bq1, bk1, bv1, bs1,
                                                 q, kv8, s, N_NODES);

    attn_k<<<attn_blocks, 256, 0, stream>>>(q, kv8, s, off, esrc, hb, nullptr,
                                            1, 1, N_NODES);

    // layer 2 (bf16 h)
    gemm_mfma_k<<<gblocks, 256, 0, stream>>>(hb, 0, wt + 4 * FD * FD, bq2, bk2, bv2, bs2,
                                             q, kv8, s, N_NODES);
    attn_k<<<attn_blocks, 256, 0, stream>>>(q, kv8, s, off, esrc, nullptr, out,
                                            0, 0, N_NODES);
}

// Round 6
// 237.283 us; speedup vs baseline: 1.0971x; 1.0971x over previous
//
#include <hip/hip_runtime.h>
#include <math.h>

#define N_NODES 50000
#define N_EDGES 800000
#define FD 128

#define NBUCK 256         // buckets: dst>>8 -> 0..195 used
#define NBUSED 196        // ceil(50000/256)
#define BCAP  6144        // entries per bucket (mean 4096, sigma~64 -> +32 sigma)
#define MAXIT 24          // BCAP/256

// ---- workspace layout (bytes) ----
#define WS_BCUR   0u          // int[256] (memset 1024 B)
#define WS_OFF    400256u     // int[N+1] -> 600260 (written fully by uber_k)
#define WS_ESRC   601728u     // ushort[E] -> 2201728
#define WS_WT     3801600u    // bf16[8*128*128] -> 4063744
#define WS_HB     16863744u   // bf16[N*128]; ALSO aliased as bin staging (disjoint lifetime)
#define WS_STAGE  16863744u   // uint32[196*6144] = 4.82 MB -> 21680640
#define WS_Q      29663744u   // bf16[N*128]
#define WS_KV     42463744u   // fp8[N*256] interleaved k|v -> 55263744
#define WS_S      68063744u   // bf16[N*128], ends 80863744

typedef unsigned short ushort_t;
typedef unsigned int uint_t;
typedef unsigned char uchar_t;
typedef __attribute__((ext_vector_type(8))) short short8;
typedef __attribute__((ext_vector_type(4))) float floatx4;
typedef __attribute__((ext_vector_type(2))) float floatx2;

__device__ __forceinline__ ushort_t f2bf(float f) {
    uint_t u = __float_as_uint(f);
    return (ushort_t)((u + 0x7FFFu + ((u >> 16) & 1u)) >> 16);   // RNE
}
__device__ __forceinline__ float bf2f_lo(uint_t u) { return __uint_as_float(u << 16); }
__device__ __forceinline__ float bf2f_hi(uint_t u) { return __uint_as_float(u & 0xFFFF0000u); }

// ---------------- prep: W->W^T bf16 (blocks 0..63) + edge binning (64..) ----------------
__global__ __launch_bounds__(256) void prep_k(
    const float* __restrict__ W0, const float* __restrict__ W1,
    const float* __restrict__ W2, const float* __restrict__ W3,
    const float* __restrict__ W4, const float* __restrict__ W5,
    const float* __restrict__ W6, const float* __restrict__ W7,
    ushort_t* __restrict__ Wt,
    const int* __restrict__ ei,
    int* __restrict__ bcur, uint_t* __restrict__ staging)
{
    if (blockIdx.x < 64) {
        const int m = blockIdx.x >> 3;
        const int sl = blockIdx.x & 7;
        const float* W = (m==0)?W0:(m==1)?W1:(m==2)?W2:(m==3)?W3:(m==4)?W4:(m==5)?W5:(m==6)?W6:W7;
        ushort_t* O = Wt + m * (FD * FD);
        #pragma unroll
        for (int it = 0; it < 2; ++it) {
            int i = threadIdx.x + it * 256 + sl * 512;   // 0..4095
            int n = i & 127, k4 = (i >> 7) << 2;
            ushort_t p[4];
            p[0] = f2bf(W[(k4 + 0) * FD + n]);
            p[1] = f2bf(W[(k4 + 1) * FD + n]);
            p[2] = f2bf(W[(k4 + 2) * FD + n]);
            p[3] = f2bf(W[(k4 + 3) * FD + n]);
            *(ushort4*)(O + n * FD + k4) = *(ushort4*)p;   // Wt[n][k]
        }
    } else {
        __shared__ int lhist[NBUCK];
        __shared__ int lbase[NBUCK];
        const int tid = threadIdx.x;
        const int base = (blockIdx.x - 64) * 2048 + tid * 8;   // E % 8 == 0
        lhist[tid] = 0;
        __syncthreads();

        uint_t pk[8];
        int li[8];
        const bool act = (base < N_EDGES);
        if (act) {
            int4 s0 = *(const int4*)(ei + base);
            int4 s1 = *(const int4*)(ei + base + 4);
            int4 d0 = *(const int4*)(ei + N_EDGES + base);
            int4 d1 = *(const int4*)(ei + N_EDGES + base + 4);
            int srcs[8] = {s0.x, s0.y, s0.z, s0.w, s1.x, s1.y, s1.z, s1.w};
            int dsts[8] = {d0.x, d0.y, d0.z, d0.w, d1.x, d1.y, d1.z, d1.w};
            #pragma unroll
            for (int j = 0; j < 8; ++j) {
                li[j] = atomicAdd(&lhist[dsts[j] >> 8], 1);
                pk[j] = (uint_t)srcs[j] | ((uint_t)dsts[j] << 16);
            }
        }
        __syncthreads();
        lbase[tid] = atomicAdd(&bcur[tid], lhist[tid]);
        __syncthreads();
        if (act) {
            #pragma unroll
            for (int j = 0; j < 8; ++j) {
                int bk = pk[j] >> 24;       // dst>>8
                staging[bk * BCAP + lbase[bk] + li[j]] = pk[j];
            }
        }
    }
}

// ---------------- shared GEMM body: 64-row tile, O_m = X @ W_m + b_m, m=0..3 ----------------
// 52 KB LDS -> 3 blocks/CU (occupancy/latency-bound regime; 128-row tile regressed).
__device__ __forceinline__ void gemm_body(
    int bid, ushort_t (*As)[136], ushort_t (*Bs)[136],
    const void* __restrict__ Xin, int x_is_fp32,
    const ushort_t* __restrict__ Wt,
    const float* __restrict__ b0, const float* __restrict__ b1,
    const float* __restrict__ b2, const float* __restrict__ b3,
    ushort_t* __restrict__ Oq, uchar_t* __restrict__ Okv,
    ushort_t* __restrict__ Os, int N)
{
    const int tid = threadIdx.x;
    const int row0 = bid * 64;

    // ---- stage X tile ----
    if (x_is_fp32) {
        const float* Xf = (const float*)Xin;
        #pragma unroll
        for (int it = 0; it < 8; ++it) {
            int i = tid + it * 256;          // 2048 float4 chunks
            int r = i >> 5, c4 = (i & 31) * 4;
            int gr = row0 + r;
            float4 xv = make_float4(0.f, 0.f, 0.f, 0.f);
            if (gr < N) xv = *(const float4*)(Xf + (size_t)gr * FD + c4);
            ushort_t p[4] = {f2bf(xv.x), f2bf(xv.y), f2bf(xv.z), f2bf(xv.w)};
            *(ushort4*)(&As[r][c4]) = *(ushort4*)p;
        }
    } else {
        const ushort_t* Xb = (const ushort_t*)Xin;
        #pragma unroll
        for (int it = 0; it < 4; ++it) {
            int i = tid + it * 256;          // 1024 x 16B chunks
            int r = i >> 4, c8 = (i & 15) * 8;
            int gr = row0 + r;
            uint4 val = make_uint4(0, 0, 0, 0);
            if (gr < N) val = *(const uint4*)(Xb + (size_t)gr * FD + c8);
            *(uint4*)(&As[r][c8]) = val;
        }
    }
    __syncthreads();

    const int wid = tid >> 6, lane = tid & 63;
    const int quad = lane >> 4, col_l = lane & 15;
    const int ar = wid * 16 + col_l;

    // ---- hoist A fragments (invariant across the 4 matrices) ----
    short8 afr[4];
    #pragma unroll
    for (int ks = 0; ks < 4; ++ks)
        afr[ks] = *(const short8*)(&As[ar][ks * 32 + quad * 8]);

    #pragma unroll 1
    for (int m = 0; m < 4; ++m) {
        const ushort_t* Wm = Wt + m * (FD * FD);
        const float* B = (m == 0) ? b0 : (m == 1) ? b1 : (m == 2) ? b2 : b3;

        // stage Bs = W^T[m] (straight copy, coalesced, padded rows)
        #pragma unroll
        for (int it = 0; it < 8; ++it) {
            int i = tid + it * 256;          // 2048 x 16B chunks
            int r = i >> 4, c8 = (i & 15) * 8;
            *(uint4*)(&Bs[r][c8]) = *(const uint4*)(Wm + (size_t)r * FD + c8);
        }
        __syncthreads();   // Bs ready; also orders prev C-tile reads vs new C-writes

        floatx4 acc[8];
        #pragma unroll
        for (int nt = 0; nt < 8; ++nt) acc[nt] = (floatx4){0.f, 0.f, 0.f, 0.f};

        #pragma unroll
        for (int ks = 0; ks < 4; ++ks) {
            const int kb = ks * 32 + quad * 8;
            #pragma unroll
            for (int nt = 0; nt < 8; ++nt) {
                short8 b = *(const short8*)(&Bs[nt * 16 + col_l][kb]);
                acc[nt] = __builtin_amdgcn_mfma_f32_16x16x32_bf16(afr[ks], b, acc[nt], 0, 0, 0);
            }
        }

        // C -> LDS (reuse As), add bias
        #pragma unroll
        for (int nt = 0; nt < 8; ++nt) {
            const int col = nt * 16 + col_l;
            const float bv = B[col];
            #pragma unroll
            for (int r = 0; r < 4; ++r)
                As[wid * 16 + quad * 4 + r][col] = f2bf(acc[nt][r] + bv);
        }
        __syncthreads();   // C tile ready

        if (m == 1 || m == 2) {
            // k/v output: bf16 C tile -> fp8 e4m3, interleaved kv row (k at +0, v at +128)
            uchar_t* O8 = Okv + ((m == 1) ? 0 : 128);
            #pragma unroll
            for (int it = 0; it < 4; ++it) {
                int i = tid + it * 256;      // 1024 chunks of 8 cols
                int r = i >> 4, c8 = (i & 15) * 8;
                int gr = row0 + r;
                if (gr < N) {
                    uint4 cb = *(const uint4*)(&As[r][c8]);
                    int lo = __builtin_amdgcn_cvt_pk_fp8_f32(bf2f_lo(cb.x), bf2f_hi(cb.x), 0, false);
                    lo = __builtin_amdgcn_cvt_pk_fp8_f32(bf2f_lo(cb.y), bf2f_hi(cb.y), lo, true);
                    int hi = __builtin_amdgcn_cvt_pk_fp8_f32(bf2f_lo(cb.z), bf2f_hi(cb.z), 0, false);
                    hi = __builtin_amdgcn_cvt_pk_fp8_f32(bf2f_lo(cb.w), bf2f_hi(cb.w), hi, true);
                    *(uint2*)(O8 + ((size_t)gr << 8) + c8) = make_uint2((uint_t)lo, (uint_t)hi);
                }
            }
        } else {
            ushort_t* O = (m == 0) ? Oq : Os;
            #pragma unroll
            for (int it = 0; it < 4; ++it) {
                int i = tid + it * 256;      // 1024 x 16B chunks
                int r = i >> 4, c8 = (i & 15) * 8;
                int gr = row0 + r;
                if (gr < N) *(uint4*)(O + (size_t)gr * FD + c8) = *(const uint4*)(&As[r][c8]);
            }
        }
    }
}

// standalone GEMM (layer 2)
__global__ __launch_bounds__(256) void gemm_mfma_k(
    const void* __restrict__ Xin, int x_is_fp32,
    const ushort_t* __restrict__ Wt,
    const float* __restrict__ b0, const float* __restrict__ b1,
    const float* __restrict__ b2, const float* __restrict__ b3,
    ushort_t* __restrict__ Oq, uchar_t* __restrict__ Okv,
    ushort_t* __restrict__ Os, int N)
{
    __shared__ ushort_t As[64][136];
    __shared__ ushort_t Bs[128][136];
    gemm_body(blockIdx.x, As, Bs, Xin, x_is_fp32, Wt, b0, b1, b2, b3, Oq, Okv, Os, N);
}

// ---------------- uber: per-bucket CSR build (blocks 0..195) + layer-1 GEMM (196..) ----------------
__global__ __launch_bounds__(256) void uber_k(
    const uint_t* __restrict__ staging, const int* __restrict__ bcur,
    int* __restrict__ off, ushort_t* __restrict__ esrc,
    const void* __restrict__ Xin, const ushort_t* __restrict__ Wt,
    const float* __restrict__ b0, const float* __restrict__ b1,
    const float* __restrict__ b2, const float* __restrict__ b3,
    ushort_t* __restrict__ Oq, uchar_t* __restrict__ Okv,
    ushort_t* __restrict__ Os, int N)
{
    __shared__ ushort_t As[64][136];
    __shared__ ushort_t Bs[128][136];
    __shared__ int s_base, s_cnt;

    if (blockIdx.x >= NBUSED) {
        gemm_body(blockIdx.x - NBUSED, As, Bs, Xin, 1, Wt, b0, b1, b2, b3, Oq, Okv, Os, N);
        return;
    }

    const int b = blockIdx.x;
    const int tid = threadIdx.x;
    int* lds  = (int*)&As[0][0];
    int* hist = lds;                      // [256] counts -> exclusive bases
    int* sbuf = lds + 256;                // [256] scan buffer

    // bucket-count prefix (parallel scan over bcur)
    int bc = (tid < NBUSED) ? bcur[tid] : 0;
    sbuf[tid] = bc;
    __syncthreads();
    #pragma unroll
    for (int d = 1; d < 256; d <<= 1) {
        int t = (tid >= d) ? sbuf[tid - d] : 0;
        __syncthreads();
        sbuf[tid] += t;
        __syncthreads();
    }
    if (tid == b) { s_base = sbuf[tid] - bc; s_cnt = bc; }
    hist[tid] = 0;
    __syncthreads();
    const int count = s_cnt;
    const int base  = s_base;
    const uint_t* st = staging + b * BCAP;

    // phase 1: histogram + per-edge rank (single LDS-atomic pass)
    int li[MAXIT];
    #pragma unroll
    for (int it = 0; it < MAXIT; ++it) {
        int i = tid + it * 256;
        if (i < count) {
            int d = (st[i] >> 16) & 255;
            li[it] = atomicAdd(&hist[d], 1);
        }
    }
    __syncthreads();

    // phase 2: exclusive scan of hist[256] (1 per thread)
    int h = hist[tid];
    sbuf[tid] = h;
    __syncthreads();
    #pragma unroll
    for (int d = 1; d < 256; d <<= 1) {
        int t = (tid >= d) ? sbuf[tid - d] : 0;
        __syncthreads();
        sbuf[tid] += t;
        __syncthreads();
    }
    const int excl = sbuf[tid] - h;
    hist[tid] = excl;
    const int dst = (b << 8) + tid;
    if (dst < N) off[dst] = base + excl;
    if (b == 0 && tid == 0) off[N] = N_EDGES;
    __syncthreads();

    // phase 3: atomic-free scatter
    #pragma unroll
    for (int it = 0; it < MAXIT; ++it) {
        int i = tid + it * 256;
        if (i < count) {
            uint_t pkv = st[i];
            int d = (pkv >> 16) & 255;
            esrc[base + hist[d] + li[it]] = (ushort_t)(pkv & 0xFFFFu);
        }
    }
}

// ---------------- per-dst attention ----------------
// 4 lane-groups of 16; 4 edge slots per group -> 16 edges per iteration.
// Interleaved fp8 kv rows (256 B: k|v adjacent), packed f32 math, packed reductions.
__global__ __launch_bounds__(256) void attn_k(
    const ushort_t* __restrict__ q, const uchar_t* __restrict__ kv8,
    const ushort_t* __restrict__ sp,
    const int* __restrict__ off, const ushort_t* __restrict__ esrc,
    ushort_t* __restrict__ out_bf, float* __restrict__ out_f,
    int relu, int bf16out, int N)
{
    const int wid = threadIdx.x >> 6;
    const int lane = threadIdx.x & 63;
    const int g = lane >> 4;         // edge-slot lane-group 0..3
    const int j = lane & 15;         // feature slice within group (8 feats)
    const int dst = blockIdx.x * 4 + wid;
    if (dst >= N) return;

    const int beg = off[dst];
    const int end = off[dst + 1];
    const int f0 = j * 8;

    const uint4 qu = *(const uint4*)(q + ((size_t)dst << 7) + f0);   // 8 bf16
    floatx2 qf2[4];
    qf2[0] = (floatx2){bf2f_lo(qu.x), bf2f_hi(qu.x)};
    qf2[1] = (floatx2){bf2f_lo(qu.y), bf2f_hi(qu.y)};
    qf2[2] = (floatx2){bf2f_lo(qu.z), bf2f_hi(qu.z)};
    qf2[3] = (floatx2){bf2f_lo(qu.w), bf2f_hi(qu.w)};

    const float scale2 = 0.1275174477f;   // (1/sqrt(128)) * log2(e)
    float l = 0.f;
    floatx2 acc2[4];
    #pragma unroll
    for (int i = 0; i < 4; ++i) acc2[i] = (floatx2){0.f, 0.f};

    const int last = end - 1;
    for (int base = beg; base < end; base += 16) {
        // ---- 16 edges: slot c covers edges base+c*4+g across the 4 groups ----
        int e[4], s[4];
        #pragma unroll
        for (int c = 0; c < 4; ++c) {
            e[c] = base + c * 4 + g;
            int idx = (e[c] <= last) ? e[c] : last;
            s[c] = esrc[idx];
        }
        uint2 kk[4], vv[4];
        #pragma unroll
        for (int c = 0; c < 4; ++c) {
            const uchar_t* row = kv8 + ((uint_t)s[c] << 8) + f0;
            kk[c] = *(const uint2*)(row);         // 8 fp8 of k
            vv[c] = *(const uint2*)(row + 128);   // 8 fp8 of v (same 256B row)
        }

        // ---- QK partial dots (packed f32) ----
        float p[4];
        #pragma unroll
        for (int c = 0; c < 4; ++c) {
            floatx2 ka = __builtin_amdgcn_cvt_pk_f32_fp8(kk[c].x, false);
            floatx2 kb = __builtin_amdgcn_cvt_pk_f32_fp8(kk[c].x, true);
            floatx2 kc = __builtin_amdgcn_cvt_pk_f32_fp8(kk[c].y, false);
            floatx2 kd = __builtin_amdgcn_cvt_pk_f32_fp8(kk[c].y, true);
            floatx2 pa = qf2[0] * ka;
            pa = qf2[1] * kb + pa;
            pa = qf2[2] * kc + pa;
            pa = qf2[3] * kd + pa;
            p[c] = pa.x + pa.y;
        }

        // ---- 16-lane reduction of 4 logits (two packed pairs) ----
        floatx2 p01 = {p[0], p[1]};
        floatx2 p23 = {p[2], p[3]};
        #pragma unroll
        for (int i = 1; i <= 8; i <<= 1) {
            long long t0 = __shfl_xor(*(long long*)&p01, i, 64);
            long long t1 = __shfl_xor(*(long long*)&p23, i, 64);
            p01 += *(const floatx2*)&t0;
            p23 += *(const floatx2*)&t1;
        }
        p01 *= scale2;
        p23 *= scale2;

        float w[4];
        w[0] = __builtin_amdgcn_exp2f(p01.x);
        w[1] = __builtin_amdgcn_exp2f(p01.y);
        w[2] = __builtin_amdgcn_exp2f(p23.x);
        w[3] = __builtin_amdgcn_exp2f(p23.y);
        #pragma unroll
        for (int c = 0; c < 4; ++c)
            if (e[c] > last) w[c] = 0.f;

        l += (w[0] + w[1]) + (w[2] + w[3]);

        // ---- PV accumulate (packed f32) ----
        #pragma unroll
        for (int c = 0; c < 4; ++c) {
            floatx2 va = __builtin_amdgcn_cvt_pk_f32_fp8(vv[c].x, false);
            floatx2 vb = __builtin_amdgcn_cvt_pk_f32_fp8(vv[c].x, true);
            floatx2 vc = __builtin_amdgcn_cvt_pk_f32_fp8(vv[c].y, false);
            floatx2 vd = __builtin_amdgcn_cvt_pk_f32_fp8(vv[c].y, true);
            const floatx2 wv = {w[c], w[c]};
            acc2[0] = wv * va + acc2[0];
            acc2[1] = wv * vb + acc2[1];
            acc2[2] = wv * vc + acc2[2];
            acc2[3] = wv * vd + acc2[3];
        }
    }

    // ---- cross-group reduction (xor 16, 32) ----
    #pragma unroll
    for (int i = 0; i < 4; ++i) {
        long long t = __shfl_xor(*(long long*)&acc2[i], 16, 64);
        acc2[i] += *(const floatx2*)&t;
        t = __shfl_xor(*(long long*)&acc2[i], 32, 64);
        acc2[i] += *(const floatx2*)&t;
    }
    l += __shfl_xor(l, 16, 64);
    l += __shfl_xor(l, 32, 64);

    const float inv = 1.0f / ((l == 0.f) ? 1.f : l);
    const int fo = f0 + g * 2;                          // lane stores 2 feats
    const uint_t su = *(const uint_t*)(sp + ((size_t)dst << 7) + fo);
    float ox = acc2[g].x * inv + bf2f_lo(su);
    float oy = acc2[g].y * inv + bf2f_hi(su);
    if (relu) { ox = fmaxf(ox, 0.f); oy = fmaxf(oy, 0.f); }
    if (bf16out) {
        ushort_t p2[2] = {f2bf(ox), f2bf(oy)};
        *(uint_t*)(out_bf + ((size_t)dst << 7) + fo) = *(uint_t*)p2;
    } else {
        *(float2*)(out_f + ((size_t)dst << 7) + fo) = make_float2(ox, oy);
    }
}

// ---------------- launch ----------------
extern "C" void kernel_launch(void* const* d_in, const int* in_sizes, int n_in,
                              void* d_out, int out_size, void* d_ws, size_t ws_size,
                              hipStream_t stream) {
    const float* x  = (const float*)d_in[0];
    const int*   ei = (const int*)d_in[1];   // [2,E]: row0=src, row1=dst
    const float* Wq1 = (const float*)d_in[2],  *bq1 = (const float*)d_in[3];
    const float* Wk1 = (const float*)d_in[4],  *bk1 = (const float*)d_in[5];
    const float* Wv1 = (const float*)d_in[6],  *bv1 = (const float*)d_in[7];
    const float* Ws1 = (const float*)d_in[8],  *bs1 = (const float*)d_in[9];
    const float* Wq2 = (const float*)d_in[10], *bq2 = (const float*)d_in[11];
    const float* Wk2 = (const float*)d_in[12], *bk2 = (const float*)d_in[13];
    const float* Wv2 = (const float*)d_in[14], *bv2 = (const float*)d_in[15];
    const float* Ws2 = (const float*)d_in[16], *bs2 = (const float*)d_in[17];

    char* ws = (char*)d_ws;
    int* bcur    = (int*)(ws + WS_BCUR);
    int* off     = (int*)(ws + WS_OFF);
    ushort_t* esrc = (ushort_t*)(ws + WS_ESRC);
    ushort_t* wt = (ushort_t*)(ws + WS_WT);
    uint_t* staging = (uint_t*)(ws + WS_STAGE);
    ushort_t* hb = (ushort_t*)(ws + WS_HB);
    ushort_t* q  = (ushort_t*)(ws + WS_Q);
    uchar_t*  kv8 = (uchar_t*)(ws + WS_KV);
    ushort_t* s  = (ushort_t*)(ws + WS_S);
    float* out = (float*)d_out;

    const int gblocks = (N_NODES + 63) / 64;          // 782
    const int attn_blocks = (N_NODES + 3) / 4;        // 12500
    const int binblocks = (N_EDGES + 2047) / 2048;    // 391

    // zero bucket cursors only
    hipMemsetAsync(ws + WS_BCUR, 0, 1024, stream);

    // fused: weight transpose (blocks 0..63) + edge binning (64..)
    prep_k<<<64 + binblocks, 256, 0, stream>>>(Wq1, Wk1, Wv1, Ws1, Wq2, Wk2, Wv2, Ws2,
                                               wt, ei, bcur, staging);

    // fused: per-bucket CSR build (196 blocks) + layer-1 GEMM (782 blocks)
    uber_k<<<NBUSED + gblocks, 256, 0, stream>>>(staging, bcur, off, esrc,
                                                 x, wt, bq1, bk1, bv1, bs1,
                                                 q, kv8, s, N_NODES);

    attn_k<<<attn_blocks, 256, 0, stream>>>(q, kv8, s, off, esrc, hb, nullptr,
                                            1, 1, N_NODES);

    // layer 2 (bf16 h)
    gemm_mfma_k<<<gblocks, 256, 0, stream>>>(hb, 0, wt + 4 * FD * FD, bq2, bk2, bv2, bs2,
                                             q, kv8, s, N_NODES);
    attn_k<<<attn_blocks, 256, 0, stream>>>(q, kv8, s, off, esrc, nullptr, out,
                                            0, 0, N_NODES);
}